// Round 1
// baseline (876.767 us; speedup 1.0000x reference)
//
#include <hip/hip_runtime.h>
#include <stdint.h>

// ---------------------------------------------------------------------------
// LogSparse attention (B=4, T=2048, E=512, H=8, head_dim=64, q/k width e=512)
// Pipeline:
//   0) convert x, w_qk to bf16; transpose+convert w_v, w_proj to [N][K] bf16
//   1) QK = x @ w_qk^T           (bf16 MFMA GEMM, C bf16 [8192][8192])
//   2) V  = x @ w_v + b_v        (bf16 MFMA GEMM, stored transposed [b,h,d,t])
//   3) flash attention with analytic log-sparse mask -> ctx bf16 [8192][512]
//   4) out = ctx @ w_proj + b_proj (f32 out)
// Workspace use: 162 MB.
// ---------------------------------------------------------------------------

typedef __attribute__((ext_vector_type(8))) short short8;
typedef __attribute__((ext_vector_type(4))) float f32x4;
typedef __attribute__((ext_vector_type(4))) unsigned short us4;

__device__ __forceinline__ f32x4 fzero4() { f32x4 z = {0.f, 0.f, 0.f, 0.f}; return z; }

__device__ __forceinline__ unsigned short f2bf(float f) {  // RNE f32->bf16
  unsigned u = __float_as_uint(f);
  u += 0x7fff + ((u >> 16) & 1);
  return (unsigned short)(u >> 16);
}

__device__ __forceinline__ void gload_lds16(const void* g, void* l) {
  __builtin_amdgcn_global_load_lds((const __attribute__((address_space(1))) void*)g,
                                   (__attribute__((address_space(3))) void*)l, 16, 0, 0);
}

// Analytic replication of _log_mask(2048, 64): sub_len=64, log_l=6.
// Rows i < 384 are fully causal. For i >= 384: with d=i-j, t=d%64,
// segment base is_ = i - 64*floor(d/64); active iff
//   is_ >= 5 : t in {0..5} u {6,7,9,13,21,37}
//   is_ <  5 : 1 <= t <= is_   (terminal "mask[:i]" branch)
__device__ __forceinline__ bool log_mask_active(int i, int j) {
  if (j > i) return false;
  if (i < 384) return true;
  const int d = i - j;
  const int t = d & 63;
  const int is_ = i - (d & ~63);
  if (is_ >= 5) return (t <= 7) || (t == 9) || (t == 13) || (t == 21) || (t == 37);
  return (t >= 1) && (t <= is_);
}

// ---------------------------------------------------------------------------
// GEMM: C[M,N] = A[M,K] * B[N,K]^T  (A,B bf16 row-major, K-contiguous)
// 128x128 tile, BK=32, 256 threads (4 waves, 2x2), 16x16x32 bf16 MFMA.
// EPI 0: C bf16 row-major, no bias
// EPI 1: V epilogue: bf16, +bias, stored transposed V_t[(b*512+col)][t]
// EPI 2: C f32 row-major, +bias
// ---------------------------------------------------------------------------
template <int EPI>
__global__ __launch_bounds__(256, 2) void gemm_bt(const unsigned short* __restrict__ A,
                                                  const unsigned short* __restrict__ B,
                                                  void* __restrict__ Cout,
                                                  const float* __restrict__ bias,
                                                  int M, int N, int K) {
  __shared__ unsigned short As[128 * 32];
  __shared__ unsigned short Bs[128 * 32];
  const int tid = threadIdx.x;
  const int wid = tid >> 6;
  const int lane = tid & 63;
  const int wm = wid >> 1, wn = wid & 1;
  const long m0 = (long)blockIdx.x * 128;
  const long n0 = (long)blockIdx.y * 128;

  f32x4 acc[4][4];
#pragma unroll
  for (int i = 0; i < 4; ++i)
#pragma unroll
    for (int j = 0; j < 4; ++j) acc[i][j] = fzero4();

  const int lrow = tid >> 2;          // 0..63
  const int lcol = (tid & 3) * 8;     // 0,8,16,24
  const unsigned short* Ag = A + (m0 + lrow) * (long)K + lcol;
  const unsigned short* Bg = B + (n0 + lrow) * (long)K + lcol;
  unsigned short* Asl = As + tid * 8;
  unsigned short* Bsl = Bs + tid * 8;
  const long K64 = (long)64 * K;

  const int fr = lane & 15;
  const int fk = (lane >> 4) * 8;

  for (int k0 = 0; k0 < K; k0 += 32) {
    gload_lds16(Ag + k0, Asl);
    gload_lds16(Ag + K64 + k0, Asl + 2048);
    gload_lds16(Bg + k0, Bsl);
    gload_lds16(Bg + K64 + k0, Bsl + 2048);
    __syncthreads();
    short8 af[4], bfr[4];
#pragma unroll
    for (int i = 0; i < 4; ++i) af[i] = *(const short8*)&As[(wm * 64 + i * 16 + fr) * 32 + fk];
#pragma unroll
    for (int j = 0; j < 4; ++j) bfr[j] = *(const short8*)&Bs[(wn * 64 + j * 16 + fr) * 32 + fk];
#pragma unroll
    for (int i = 0; i < 4; ++i)
#pragma unroll
      for (int j = 0; j < 4; ++j)
        acc[i][j] = __builtin_amdgcn_mfma_f32_16x16x32_bf16(af[i], bfr[j], acc[i][j], 0, 0, 0);
    __syncthreads();
  }

  const int fg = lane >> 4;
#pragma unroll
  for (int i = 0; i < 4; ++i) {
#pragma unroll
    for (int j = 0; j < 4; ++j) {
      const long row0 = m0 + wm * 64 + i * 16 + fg * 4;  // +r
      const long col = n0 + wn * 64 + j * 16 + fr;
      if (EPI == 0) {
        unsigned short* C = (unsigned short*)Cout;
#pragma unroll
        for (int r = 0; r < 4; ++r) C[(row0 + r) * (long)N + col] = f2bf(acc[i][j][r]);
      } else if (EPI == 1) {
        unsigned short* C = (unsigned short*)Cout;
        const float bs = bias[col];
        const int b_ = (int)(row0 >> 11);
        const int t0 = (int)(row0 & 2047);
        us4 pk;
#pragma unroll
        for (int r = 0; r < 4; ++r) pk[r] = f2bf(acc[i][j][r] + bs);
        *(us4*)&C[((size_t)(b_ * 512 + col)) * 2048 + t0] = pk;  // [b,h,d][t]
      } else {
        float* C = (float*)Cout;
        const float bs = bias[col];
#pragma unroll
        for (int r = 0; r < 4; ++r) C[(row0 + r) * (long)N + col] = acc[i][j][r] + bs;
      }
    }
  }
}

// ---------------------------------------------------------------------------
// Flash attention with analytic log-sparse mask.
// Grid: 1024 blocks = (b*8+h)*32 + qt. 256 threads = 4 waves.
// Per block: 64 q-rows; wave w owns rows w*16..w*16+15 (softmax in-register).
// Q in registers (16 x short8 / lane). K staged in LDS in 64x256 e-chunks.
// V pre-transposed [d][t] so PV B-fragment reads are contiguous.
// ---------------------------------------------------------------------------
__global__ __launch_bounds__(256, 2) void flash_attn(const unsigned short* __restrict__ QK,
                                                     const unsigned short* __restrict__ Vt,
                                                     unsigned short* __restrict__ ctx) {
  __shared__ unsigned short Klds[64 * 256];   // 32 KB: [key 64][e 256]
  __shared__ unsigned short Vlds[64 * 64];    // 8 KB:  [d 64][k 64]
  __shared__ unsigned short Plds[4][16 * 64]; // 8 KB:  per-wave [qrow 16][k 64]

  const int tid = threadIdx.x, wid = tid >> 6, lane = tid & 63;
  const int fr = lane & 15, fg = lane >> 4;
  const int blk = blockIdx.x;
  const int qt = blk & 31, bh = blk >> 5;
  const int b = bh >> 3, h = bh & 7;

  // Q rows for this wave -> registers (A fragments for all 16 e-steps)
  short8 qreg[16];
  {
    const unsigned short* qp =
        QK + (size_t)(b * 2048 + qt * 64 + wid * 16 + fr) * 8192 + h * 512 + fg * 8;
#pragma unroll
    for (int e = 0; e < 16; ++e) qreg[e] = *(const short8*)(qp + e * 32);
  }

  f32x4 o[4];
#pragma unroll
  for (int j = 0; j < 4; ++j) o[j] = fzero4();
  float mr[4] = {-1e30f, -1e30f, -1e30f, -1e30f};
  float lr[4] = {0.f, 0.f, 0.f, 0.f};

  const int vrow = tid >> 3, vcol = (tid & 7) * 8;
  const int krow = tid >> 5, kcol = (tid & 31) * 8;

  for (int kt = 0; kt <= qt; ++kt) {  // causal: skip above-diagonal tiles
    // V tile: Vt rows are d (64 of them), cols kt*64..+63
    gload_lds16(Vt + (size_t)(bh * 64 + vrow) * 2048 + kt * 64 + vcol, &Vlds[tid * 8]);
    gload_lds16(Vt + (size_t)(bh * 64 + 32 + vrow) * 2048 + kt * 64 + vcol, &Vlds[2048 + tid * 8]);

    f32x4 s[4];
#pragma unroll
    for (int j = 0; j < 4; ++j) s[j] = fzero4();

#pragma unroll
    for (int c = 0; c < 2; ++c) {  // two 256-wide e-chunks of K
      const unsigned short* kg = QK + (size_t)(b * 2048 + kt * 64 + krow) * 8192 + 4096 +
                                 h * 512 + c * 256 + kcol;
#pragma unroll
      for (int i = 0; i < 8; ++i) gload_lds16(kg + (size_t)i * 8 * 8192, &Klds[i * 2048 + tid * 8]);
      __syncthreads();
#pragma unroll
      for (int e = 0; e < 8; ++e) {
#pragma unroll
        for (int j = 0; j < 4; ++j) {
          short8 bfr = *(const short8*)&Klds[(j * 16 + fr) * 256 + e * 32 + fg * 8];
          s[j] = __builtin_amdgcn_mfma_f32_16x16x32_bf16(qreg[c * 8 + e], bfr, s[j], 0, 0, 0);
        }
      }
      __syncthreads();
    }

    // ---- online softmax (rows = qt*64 + wid*16 + fg*4 + r, cols = kt*64 + j*16 + fr)
    const int gq0 = qt * 64 + wid * 16 + fg * 4;
    const int gk0 = kt * 64 + fr;
#pragma unroll
    for (int r = 0; r < 4; ++r) {
      float mx = -1e30f;
#pragma unroll
      for (int j = 0; j < 4; ++j) {
        float v = s[j][r] * 0.125f;  // SCALE = 64^-0.5
        v = log_mask_active(gq0 + r, gk0 + j * 16) ? v : -1e30f;
        s[j][r] = v;
        mx = fmaxf(mx, v);
      }
#pragma unroll
      for (int d = 1; d < 16; d <<= 1) mx = fmaxf(mx, __shfl_xor(mx, d));
      const float mnew = fmaxf(mr[r], mx);
      const float alpha = __expf(mr[r] - mnew);  // -1e30 init -> 0, never NaN
      float psum = 0.f;
#pragma unroll
      for (int j = 0; j < 4; ++j) {
        float p = __expf(s[j][r] - mnew);  // masked (-1e30) -> exp(-huge) = 0
        s[j][r] = p;
        psum += p;
      }
#pragma unroll
      for (int d = 1; d < 16; d <<= 1) psum += __shfl_xor(psum, d);
      lr[r] = lr[r] * alpha + psum;
      mr[r] = mnew;
#pragma unroll
      for (int jd = 0; jd < 4; ++jd) o[jd][r] *= alpha;
    }

    // P -> LDS (bf16), per-wave private region
#pragma unroll
    for (int r = 0; r < 4; ++r)
#pragma unroll
      for (int j = 0; j < 4; ++j)
        Plds[wid][(fg * 4 + r) * 64 + j * 16 + fr] = f2bf(s[j][r]);

    // ---- PV: O[16 x 64] += P[16 x 64] * V[64 x 64]
#pragma unroll
    for (int ks = 0; ks < 2; ++ks) {
      short8 pa = *(const short8*)&Plds[wid][fr * 64 + ks * 32 + fg * 8];
#pragma unroll
      for (int jd = 0; jd < 4; ++jd) {
        short8 vb = *(const short8*)&Vlds[(jd * 16 + fr) * 64 + ks * 32 + fg * 8];
        o[jd] = __builtin_amdgcn_mfma_f32_16x16x32_bf16(pa, vb, o[jd], 0, 0, 0);
      }
    }
    __syncthreads();  // protect Vlds before next iteration's staging
  }

  // epilogue: ctx[b*2048 + row][h*64 + d] = O / l
#pragma unroll
  for (int r = 0; r < 4; ++r) {
    const float inv = 1.0f / lr[r];
    unsigned short* cp =
        ctx + (size_t)(b * 2048 + qt * 64 + wid * 16 + fg * 4 + r) * 512 + h * 64;
#pragma unroll
    for (int jd = 0; jd < 4; ++jd) cp[jd * 16 + fr] = f2bf(o[jd][r] * inv);
  }
}

// ---------------------------------------------------------------------------
// Conversions
// ---------------------------------------------------------------------------
__global__ void f32_to_bf16_k(const float* __restrict__ in, unsigned short* __restrict__ out,
                              int n4) {
  const int i = blockIdx.x * 256 + threadIdx.x;
  if (i < n4) {
    const float4 v = ((const float4*)in)[i];
    us4 o;
    o[0] = f2bf(v.x);
    o[1] = f2bf(v.y);
    o[2] = f2bf(v.z);
    o[3] = f2bf(v.w);
    ((us4*)out)[i] = o;
  }
}

// out[n][k] = bf16(in[k][n]) for 512x512 weight (x @ W -> C = A * W^T form)
__global__ void transpose_w_k(const float* __restrict__ in, unsigned short* __restrict__ out) {
  const int idx = blockIdx.x * 256 + threadIdx.x;
  const int row = idx >> 9, col = idx & 511;
  out[idx] = f2bf(in[col * 512 + row]);
}

// ---------------------------------------------------------------------------
extern "C" void kernel_launch(void* const* d_in, const int* in_sizes, int n_in,
                              void* d_out, int out_size, void* d_ws, size_t ws_size,
                              hipStream_t stream) {
  (void)in_sizes; (void)n_in; (void)out_size; (void)ws_size;
  const float* x = (const float*)d_in[0];
  const float* wqk = (const float*)d_in[1];
  const float* wv = (const float*)d_in[2];
  const float* bv = (const float*)d_in[3];
  const float* wp = (const float*)d_in[4];
  const float* bp = (const float*)d_in[5];
  // d_in[6] (mask) unused: mask computed analytically in-kernel.

  char* ws = (char*)d_ws;
  unsigned short* x_bf   = (unsigned short*)(ws + 0);                    //   8 MB [8192][512]
  unsigned short* wqk_bf = (unsigned short*)(ws + (size_t)8 * 1048576);  //   8 MB [8192][512]
  unsigned short* wv_t   = (unsigned short*)(ws + (size_t)16 * 1048576); // 0.5 MB [512][512]
  unsigned short* wp_t   = (unsigned short*)(ws + (size_t)17 * 1048576); // 0.5 MB [512][512]
  unsigned short* qk_bf  = (unsigned short*)(ws + (size_t)18 * 1048576); // 128 MB [8192][8192]
  unsigned short* v_t    = (unsigned short*)(ws + (size_t)146 * 1048576);//   8 MB [2048][2048]
  unsigned short* ctx_bf = (unsigned short*)(ws + (size_t)154 * 1048576);//   8 MB [8192][512]

  f32_to_bf16_k<<<4096, 256, 0, stream>>>(x, x_bf, 1048576);
  f32_to_bf16_k<<<4096, 256, 0, stream>>>(wqk, wqk_bf, 1048576);
  transpose_w_k<<<1024, 256, 0, stream>>>(wv, wv_t);
  transpose_w_k<<<1024, 256, 0, stream>>>(wp, wp_t);

  // QK = x @ w_qk^T : [8192][8192] bf16 (cols 0..4095 = Q, 4096..8191 = K)
  gemm_bt<0><<<dim3(64, 64), 256, 0, stream>>>(x_bf, wqk_bf, qk_bf, nullptr, 8192, 8192, 512);
  // V = x @ w_v + b_v, stored transposed [ (b*8+h)*64+d ][ t ]
  gemm_bt<1><<<dim3(64, 4), 256, 0, stream>>>(x_bf, wv_t, v_t, bv, 8192, 512, 512);

  flash_attn<<<1024, 256, 0, stream>>>(qk_bf, v_t, ctx_bf);

  // out = ctx @ w_proj + b_proj (f32)
  gemm_bt<2><<<dim3(64, 4), 256, 0, stream>>>(ctx_bf, wp_t, d_out, bp, 8192, 512, 512);
}

// Round 2
// 288.573 us; speedup vs baseline: 3.0383x; 3.0383x over previous
//
#include <hip/hip_runtime.h>
#include <stdint.h>

// ---------------------------------------------------------------------------
// LogSparse attention (B=4, T=2048, E=512, H=8, head_dim=64, q/k width e=512)
//   0) convert x, w_qk to bf16; transpose+convert w_v, w_proj to [N][K] bf16
//   1) QK = x @ w_qk^T           (bf16 MFMA GEMM, C bf16 [8192][8192])
//   2) V  = x @ w_v + b_v        (bf16 MFMA GEMM, stored transposed [b,h,d,t])
//   3) flash attention, analytic log-sparse mask -> ctx bf16 [8192][512]
//      - K double-buffered in LDS (XOR-swizzled via pre-swizzled global src)
//      - V direct global->reg (L2-resident), P via swizzled wave-private LDS
//      - mask precomputed as 3 x 16-bit register bitmaps
//      - longest-job-first block remap
//   4) out = ctx @ w_proj + b_proj (f32 out)
// ---------------------------------------------------------------------------

typedef __attribute__((ext_vector_type(8))) short short8;
typedef __attribute__((ext_vector_type(4))) float f32x4;
typedef __attribute__((ext_vector_type(4))) unsigned short us4;

__device__ __forceinline__ f32x4 fzero4() { f32x4 z = {0.f, 0.f, 0.f, 0.f}; return z; }

__device__ __forceinline__ unsigned short f2bf(float f) {  // RNE f32->bf16
  unsigned u = __float_as_uint(f);
  u += 0x7fff + ((u >> 16) & 1);
  return (unsigned short)(u >> 16);
}

__device__ __forceinline__ void gload_lds16(const void* g, void* l) {
  __builtin_amdgcn_global_load_lds((const __attribute__((address_space(1))) void*)g,
                                   (__attribute__((address_space(3))) void*)l, 16, 0, 0);
}

// ---------------------------------------------------------------------------
// GEMM: C[M,N] = A[M,K] * B[N,K]^T  (A,B bf16 row-major, K-contiguous)
// 128x128 tile, BK=32, 256 threads (4 waves, 2x2), 16x16x32 bf16 MFMA.
// EPI 0: C bf16 row-major, no bias
// EPI 1: V epilogue: bf16, +bias, stored transposed V_t[(b*512+col)][t]
// EPI 2: C f32 row-major, +bias
// ---------------------------------------------------------------------------
template <int EPI>
__global__ __launch_bounds__(256, 2) void gemm_bt(const unsigned short* __restrict__ A,
                                                  const unsigned short* __restrict__ B,
                                                  void* __restrict__ Cout,
                                                  const float* __restrict__ bias,
                                                  int M, int N, int K) {
  __shared__ unsigned short As[128 * 32];
  __shared__ unsigned short Bs[128 * 32];
  const int tid = threadIdx.x;
  const int wid = tid >> 6;
  const int lane = tid & 63;
  const int wm = wid >> 1, wn = wid & 1;
  const long m0 = (long)blockIdx.x * 128;
  const long n0 = (long)blockIdx.y * 128;

  f32x4 acc[4][4];
#pragma unroll
  for (int i = 0; i < 4; ++i)
#pragma unroll
    for (int j = 0; j < 4; ++j) acc[i][j] = fzero4();

  const int lrow = tid >> 2;          // 0..63
  const int lcol = (tid & 3) * 8;     // 0,8,16,24
  const unsigned short* Ag = A + (m0 + lrow) * (long)K + lcol;
  const unsigned short* Bg = B + (n0 + lrow) * (long)K + lcol;
  unsigned short* Asl = As + tid * 8;
  unsigned short* Bsl = Bs + tid * 8;
  const long K64 = (long)64 * K;

  const int fr = lane & 15;
  const int fk = (lane >> 4) * 8;

  for (int k0 = 0; k0 < K; k0 += 32) {
    gload_lds16(Ag + k0, Asl);
    gload_lds16(Ag + K64 + k0, Asl + 2048);
    gload_lds16(Bg + k0, Bsl);
    gload_lds16(Bg + K64 + k0, Bsl + 2048);
    __syncthreads();
    short8 af[4], bfr[4];
#pragma unroll
    for (int i = 0; i < 4; ++i) af[i] = *(const short8*)&As[(wm * 64 + i * 16 + fr) * 32 + fk];
#pragma unroll
    for (int j = 0; j < 4; ++j) bfr[j] = *(const short8*)&Bs[(wn * 64 + j * 16 + fr) * 32 + fk];
#pragma unroll
    for (int i = 0; i < 4; ++i)
#pragma unroll
      for (int j = 0; j < 4; ++j)
        acc[i][j] = __builtin_amdgcn_mfma_f32_16x16x32_bf16(af[i], bfr[j], acc[i][j], 0, 0, 0);
    __syncthreads();
  }

  const int fg = lane >> 4;
#pragma unroll
  for (int i = 0; i < 4; ++i) {
#pragma unroll
    for (int j = 0; j < 4; ++j) {
      const long row0 = m0 + wm * 64 + i * 16 + fg * 4;  // +r
      const long col = n0 + wn * 64 + j * 16 + fr;
      if (EPI == 0) {
        unsigned short* C = (unsigned short*)Cout;
#pragma unroll
        for (int r = 0; r < 4; ++r) C[(row0 + r) * (long)N + col] = f2bf(acc[i][j][r]);
      } else if (EPI == 1) {
        unsigned short* C = (unsigned short*)Cout;
        const float bs = bias[col];
        const int b_ = (int)(row0 >> 11);
        const int t0 = (int)(row0 & 2047);
        us4 pk;
#pragma unroll
        for (int r = 0; r < 4; ++r) pk[r] = f2bf(acc[i][j][r] + bs);
        *(us4*)&C[((size_t)(b_ * 512 + col)) * 2048 + t0] = pk;  // [b,h,d][t]
      } else {
        float* C = (float*)Cout;
        const float bs = bias[col];
#pragma unroll
        for (int r = 0; r < 4; ++r) C[(row0 + r) * (long)N + col] = acc[i][j][r] + bs;
      }
    }
  }
}

// ---------------------------------------------------------------------------
// Flash attention, log-sparse mask. Grid 1024 blocks, 256 threads (4 waves).
// Block -> (bh = blk&31, qt = 31-(blk>>5)): 64 q-rows, longest job first.
// Wave w owns q rows w*16..+15; softmax in-register.
// K: 4 chunks [64 keys][128 e] per k-tile, double-buffered LDS, XOR-swizzled.
// V: direct global->reg. P: wave-private swizzled LDS (no barrier).
// ---------------------------------------------------------------------------
__global__ __launch_bounds__(256, 2) void flash_attn(const unsigned short* __restrict__ QK,
                                                     const unsigned short* __restrict__ Vt,
                                                     unsigned short* __restrict__ ctx) {
  __shared__ unsigned short Kb[2][64 * 128];   // 2 x 16 KB
  __shared__ unsigned short Plds[4][16 * 64];  // 8 KB, per-wave

  const int tid = threadIdx.x, wid = tid >> 6, lane = tid & 63;
  const int fr = lane & 15, fg = lane >> 4;
  const int blk = blockIdx.x;
  const int qt = 31 - (blk >> 5);  // longest-first
  const int bh = blk & 31;
  const int b = bh >> 3, h = bh & 7;

  // ---- Q fragments -> registers (16 e-steps x 8 bf16)
  short8 qreg[16];
  {
    const unsigned short* qp =
        QK + (size_t)(b * 2048 + qt * 64 + wid * 16 + fr) * 8192 + h * 512 + fg * 8;
#pragma unroll
    for (int e = 0; e < 16; ++e) qreg[e] = *(const short8*)(qp + e * 32);
  }

  // ---- precompute mask bitmaps (bit r*4+j); circulant pattern is kt-invariant
  unsigned m_gen = 0xFFFFu, m_t0 = 0xFFFFu, m_diag = 0u;
  {
    const int lrow = wid * 16 + fg * 4;  // +r = row within q-block
    if (qt <= 5) {                       // rows < 384: plain causal
#pragma unroll
      for (int r = 0; r < 4; ++r)
#pragma unroll
        for (int j = 0; j < 4; ++j)
          if (j * 16 + fr <= lrow + r) m_diag |= 1u << (r * 4 + j);
    } else {
      m_gen = 0; m_t0 = 0;
      const unsigned long long SBITS = 0x20002022FFull;  // t in {0..7,9,13,21,37}
#pragma unroll
      for (int r = 0; r < 4; ++r) {
        const int i = qt * 64 + lrow + r;
#pragma unroll
        for (int j = 0; j < 4; ++j) {
          const int c = j * 16 + fr;
          const int t = (i - c) & 63;
          const unsigned g = (unsigned)((SBITS >> t) & 1ull);
          const unsigned bit = 1u << (r * 4 + j);
          if (g) m_gen |= bit;
          if ((c + t >= 5) ? (g != 0) : (t >= 1)) m_t0 |= bit;  // terminal rule j<5
          if (g && c <= lrow + r) m_diag |= bit;
        }
      }
    }
  }

  f32x4 o[4];
#pragma unroll
  for (int j = 0; j < 4; ++j) o[j] = fzero4();
  float mr[4] = {-1e30f, -1e30f, -1e30f, -1e30f};
  float lr[4] = {0.f, 0.f, 0.f, 0.f};

  // ---- K staging precompute (pre-swizzled global source; LDS dest linear)
  const int srow = tid >> 4;                      // row within 16-row group
  const int gslot = (tid & 15) ^ (srow & 7);      // inverse-swizzled 16B slot
  const unsigned short* Kg =
      QK + (size_t)(b * 2048 + srow) * 8192 + 4096 + h * 512 + gslot * 8;
  const int xsw = (fr & 7) * 8;                   // read-side XOR (elements)

  // prologue: stage chunk 0 (kt=0, c=0) into Kb[0]
#pragma unroll
  for (int rr = 0; rr < 4; ++rr)
    gload_lds16(Kg + (size_t)(rr * 16) * 8192, &Kb[0][rr * 2048 + tid * 8]);
  __syncthreads();

  const int nchunks = (qt + 1) * 4;
  for (int kt = 0; kt <= qt; ++kt) {
    // V tile -> registers (L2-resident; latency hides under QK chunks)
    short8 vreg[2][4];
#pragma unroll
    for (int ks = 0; ks < 2; ++ks)
#pragma unroll
      for (int jd = 0; jd < 4; ++jd)
        vreg[ks][jd] = *(const short8*)(Vt + (size_t)(bh * 64 + jd * 16 + fr) * 2048 +
                                        kt * 64 + ks * 32 + fg * 8);

    f32x4 s[4];
#pragma unroll
    for (int j = 0; j < 4; ++j) s[j] = fzero4();

#pragma unroll
    for (int c = 0; c < 4; ++c) {
      const int glob = kt * 4 + c;
      const int cur = glob & 1;
      if (glob + 1 < nchunks) {  // stage next chunk into other buffer
        const int nk = (glob + 1) >> 2, nc = (glob + 1) & 3;
        const unsigned short* src = Kg + (size_t)(nk * 64) * 8192 + nc * 128;
#pragma unroll
        for (int rr = 0; rr < 4; ++rr)
          gload_lds16(src + (size_t)(rr * 16) * 8192, &Kb[cur ^ 1][rr * 2048 + tid * 8]);
      }
#pragma unroll
      for (int e = 0; e < 4; ++e) {
#pragma unroll
        for (int j = 0; j < 4; ++j) {
          const short8 bfr =
              *(const short8*)&Kb[cur][(j * 16 + fr) * 128 + ((e * 32 + fg * 8) ^ xsw)];
          s[j] = __builtin_amdgcn_mfma_f32_16x16x32_bf16(qreg[c * 4 + e], bfr, s[j], 0, 0, 0);
        }
      }
      __syncthreads();  // drains stage (vmcnt) + hands buffer to all waves
    }

    // ---- masked online softmax (rows wave-private: 16-lane shfl reduce)
    unsigned m = (kt == 0) ? m_t0 : m_gen;
    if (kt == qt) m &= m_diag;
#pragma unroll
    for (int r = 0; r < 4; ++r) {
      float mx = -1e30f;
#pragma unroll
      for (int j = 0; j < 4; ++j) {
        float v = s[j][r] * 0.125f;  // SCALE = 64^-0.5
        v = ((m >> (r * 4 + j)) & 1u) ? v : -1e30f;
        s[j][r] = v;
        mx = fmaxf(mx, v);
      }
#pragma unroll
      for (int d = 1; d < 16; d <<= 1) mx = fmaxf(mx, __shfl_xor(mx, d));
      const float mnew = fmaxf(mr[r], mx);
      const float alpha = __expf(mr[r] - mnew);
      float ps = 0.f;
#pragma unroll
      for (int j = 0; j < 4; ++j) {
        const float p = __expf(s[j][r] - mnew);
        s[j][r] = p;
        ps += p;
      }
#pragma unroll
      for (int d = 1; d < 16; d <<= 1) ps += __shfl_xor(ps, d);
      lr[r] = lr[r] * alpha + ps;
      mr[r] = mnew;
#pragma unroll
      for (int jd = 0; jd < 4; ++jd) o[jd][r] *= alpha;
    }

    // ---- P -> wave-private LDS (swizzled both sides; no barrier needed)
#pragma unroll
    for (int r = 0; r < 4; ++r) {
      const int prow = fg * 4 + r;
#pragma unroll
      for (int j = 0; j < 4; ++j)
        Plds[wid][prow * 64 + (((j * 2 + (fr >> 3)) ^ (prow & 7)) * 8) + (fr & 7)] =
            f2bf(s[j][r]);
    }

    // ---- PV: O[16x64] += P[16x64] * V^T fragments (V in registers)
#pragma unroll
    for (int ks = 0; ks < 2; ++ks) {
      const short8 pa =
          *(const short8*)&Plds[wid][fr * 64 + (((ks * 4 + fg) ^ (fr & 7)) * 8)];
#pragma unroll
      for (int jd = 0; jd < 4; ++jd)
        o[jd] = __builtin_amdgcn_mfma_f32_16x16x32_bf16(pa, vreg[ks][jd], o[jd], 0, 0, 0);
    }
  }

  // ---- epilogue: ctx[b*2048 + row][h*64 + d] = O / l
#pragma unroll
  for (int r = 0; r < 4; ++r) {
    const float inv = 1.0f / lr[r];
    unsigned short* cp =
        ctx + (size_t)(b * 2048 + qt * 64 + wid * 16 + fg * 4 + r) * 512 + h * 64;
#pragma unroll
    for (int jd = 0; jd < 4; ++jd) cp[jd * 16 + fr] = f2bf(o[jd][r] * inv);
  }
}

// ---------------------------------------------------------------------------
// Conversions
// ---------------------------------------------------------------------------
__global__ void f32_to_bf16_k(const float* __restrict__ in, unsigned short* __restrict__ out,
                              int n4) {
  const int i = blockIdx.x * 256 + threadIdx.x;
  if (i < n4) {
    const float4 v = ((const float4*)in)[i];
    us4 o;
    o[0] = f2bf(v.x);
    o[1] = f2bf(v.y);
    o[2] = f2bf(v.z);
    o[3] = f2bf(v.w);
    ((us4*)out)[i] = o;
  }
}

// out[n][k] = bf16(in[k][n]) for 512x512 weight (x @ W -> C = A * W^T form)
__global__ void transpose_w_k(const float* __restrict__ in, unsigned short* __restrict__ out) {
  const int idx = blockIdx.x * 256 + threadIdx.x;
  const int row = idx >> 9, col = idx & 511;
  out[idx] = f2bf(in[col * 512 + row]);
}

// ---------------------------------------------------------------------------
extern "C" void kernel_launch(void* const* d_in, const int* in_sizes, int n_in,
                              void* d_out, int out_size, void* d_ws, size_t ws_size,
                              hipStream_t stream) {
  (void)in_sizes; (void)n_in; (void)out_size; (void)ws_size;
  const float* x = (const float*)d_in[0];
  const float* wqk = (const float*)d_in[1];
  const float* wv = (const float*)d_in[2];
  const float* bv = (const float*)d_in[3];
  const float* wp = (const float*)d_in[4];
  const float* bp = (const float*)d_in[5];
  // d_in[6] (mask) unused: mask computed analytically in-kernel.

  char* ws = (char*)d_ws;
  unsigned short* x_bf   = (unsigned short*)(ws + 0);                    //   8 MB [8192][512]
  unsigned short* wqk_bf = (unsigned short*)(ws + (size_t)8 * 1048576);  //   8 MB [8192][512]
  unsigned short* wv_t   = (unsigned short*)(ws + (size_t)16 * 1048576); // 0.5 MB [512][512]
  unsigned short* wp_t   = (unsigned short*)(ws + (size_t)17 * 1048576); // 0.5 MB [512][512]
  unsigned short* qk_bf  = (unsigned short*)(ws + (size_t)18 * 1048576); // 128 MB [8192][8192]
  unsigned short* v_t    = (unsigned short*)(ws + (size_t)146 * 1048576);//   8 MB [2048][2048]
  unsigned short* ctx_bf = (unsigned short*)(ws + (size_t)154 * 1048576);//   8 MB [8192][512]

  f32_to_bf16_k<<<4096, 256, 0, stream>>>(x, x_bf, 1048576);
  f32_to_bf16_k<<<4096, 256, 0, stream>>>(wqk, wqk_bf, 1048576);
  transpose_w_k<<<1024, 256, 0, stream>>>(wv, wv_t);
  transpose_w_k<<<1024, 256, 0, stream>>>(wp, wp_t);

  // QK = x @ w_qk^T : [8192][8192] bf16 (cols 0..4095 = Q, 4096..8191 = K)
  gemm_bt<0><<<dim3(64, 64), 256, 0, stream>>>(x_bf, wqk_bf, qk_bf, nullptr, 8192, 8192, 512);
  // V = x @ w_v + b_v, stored transposed [ (b*8+h)*64+d ][ t ]
  gemm_bt<1><<<dim3(64, 4), 256, 0, stream>>>(x_bf, wv_t, v_t, bv, 8192, 512, 512);

  flash_attn<<<1024, 256, 0, stream>>>(qk_bf, v_t, ctx_bf);

  // out = ctx @ w_proj + b_proj (f32)
  gemm_bt<2><<<dim3(64, 4), 256, 0, stream>>>(ctx_bf, wp_t, d_out, bp, 8192, 512, 512);
}